// Round 16
// baseline (261.342 us; speedup 1.0000x reference)
//
#include <hip/hip_runtime.h>

#define Nn 50000
#define Ee 800000

typedef _Float16 half8 __attribute__((ext_vector_type(8)));
typedef __fp16 fp16x2 __attribute__((ext_vector_type(2)));
typedef float floatx16 __attribute__((ext_vector_type(16)));

// ---- workspace layout (bytes) ----
#define SDD_OFF     0                                    // int4[Ee] (src,dst,delta f16x3)
#define DEG_OFF     (SDD_OFF + (size_t)Ee * 16)
#define OFF_OFF     (DEG_OFF + (size_t)Nn * 4)
#define BSUM_OFF    (OFF_OFF + (size_t)Nn * 4)
#define RANK_OFF    (BSUM_OFF + 256)                     // int[Ee]
#define WT_OFF      (RANK_OFF + (size_t)Ee * 4)
#define WT_HALVES   25728   // ... | Wm1c 4096 | packed-bias 128
#define WU_OFF      (WT_OFF + (size_t)WT_HALVES * 2)
#define WU_HALVES   8192
#define PQ_OFF      (WU_OFF + (size_t)WU_HALVES * 2)     // PQp f16 [Nn][128]
#define TOTAL_WS    (PQ_OFF + (size_t)Nn * 128 * 2)      // ~29 MB

// wt sub-offsets in GLOBAL packed table (halves)
#define WE1T 0
#define WE2T 1024
#define WM1T 5120
#define WM2T 17408
#define WM1C 21504   // compact e2-block of Wm1: [64][64]
#define PBIAS 25600  // packed f16 bias pairs

// LDS padded layout (halves)
#define SWE1 0
#define SWE2 1024          // stride 72
#define SWM1C 5632         // stride 72
#define SWM2 10240         // stride 72
#define SPB  14848         // packed bias, 128 halves
#define SWT_HALVES 14976   // 29952 B

// prep kernel grid partition
#define WT_NB   101
#define WU_NB   32
#define HI_NB   3125
#define PREP_NB (WT_NB + WU_NB + HI_NB)

#define SCAN_TILE 4096
#define SCAN_NBLK 13
#define FILL_NB   3125
#define PQ_NB     391      // ceil(50000/128)
#define FILLPQ_NB (FILL_NB + PQ_NB)

// ===========================================================================
// Fused prep: weight tables (+packed bias), Wu1t, histogram+rank.
// ===========================================================================
__global__ __launch_bounds__(256) void prep_kernel(
    const int* __restrict__ ei,
    const float* __restrict__ We1, const float* __restrict__ We2,
    const float* __restrict__ Wm1, const float* __restrict__ Wm2,
    const float* __restrict__ Wu1,
    const float* __restrict__ be1, const float* __restrict__ be2,
    _Float16* __restrict__ wt, _Float16* __restrict__ wu,
    int* __restrict__ deg, int* __restrict__ rank)
{
    const int b = blockIdx.x, tid = threadIdx.x;
    if (b < WT_NB) {                                   // ---- weight tables
        const int i = b * 256 + tid;
        if (i < 25728) {
            float v;
            if (i < 1024) {                      // We1t [64][16], K=3 zero-padded
                const int n = i >> 4, k = i & 15;
                v = (k < 3) ? We1[k * 64 + n] : 0.0f;
            } else if (i < 5120) {               // We2t [64][64]
                const int j = i - 1024, n = j >> 6, k = j & 63;
                v = We2[k * 64 + n];
            } else if (i < 17408) {              // Wm1t [64][192]
                const int j = i - 5120, n = j / 192, k = j - n * 192;
                v = Wm1[k * 64 + n];
            } else if (i < 21504) {              // Wm2t [64][64]
                const int j = i - 17408, n = j >> 6, k = j & 63;
                v = Wm2[k * 64 + n];
            } else if (i < 25600) {              // Wm1c [64][64] (k 128..191)
                const int j = i - 21504, n = j >> 6, k = j & 63;
                v = Wm1[(128 + k) * 64 + n];
            } else {                             // packed bias pairs
                const int t = i - 25600;         // half idx 0..127
                const int j = t >> 1, which = t & 1;
                const int layer = j >> 5, rem = j & 31;
                const int boff = (rem >> 4) & 1, kh = (rem >> 3) & 1, q = rem & 7;
                const int r = 2 * q + which;
                const int f = (r & 3) + 8 * (r >> 2) + 4 * kh + 32 * boff;
                v = layer ? be2[f] : be1[f];
            }
            wt[i] = (_Float16)v;
        }
    } else if (b < WT_NB + WU_NB) {                    // ---- Wu1t [64][128]
        const int i = (b - WT_NB) * 256 + tid;
        const int n = i >> 7, k = i & 127;
        wu[i] = (_Float16)Wu1[k * 64 + n];
    } else {                                           // ---- histogram + rank
        const int e = (b - WT_NB - WU_NB) * 256 + tid;
        rank[e] = atomicAdd(&deg[ei[Ee + e]], 1);
    }
}

// ===========================================================================
// scan1: block-local exclusive scan of deg -> off, per-block totals -> bsum.
// ===========================================================================
__global__ __launch_bounds__(1024) void scan1_kernel(const int* __restrict__ deg,
                                                     int* __restrict__ off,
                                                     int* __restrict__ bsum) {
    __shared__ int wsum[16];
    const int tid = threadIdx.x;
    const int lane = tid & 63, wid = tid >> 6;
    const int base = blockIdx.x * SCAN_TILE + tid * 4;

    int v0 = (base + 0 < Nn) ? deg[base + 0] : 0;
    int v1 = (base + 1 < Nn) ? deg[base + 1] : 0;
    int v2 = (base + 2 < Nn) ? deg[base + 2] : 0;
    int v3 = (base + 3 < Nn) ? deg[base + 3] : 0;
    const int tsum = v0 + v1 + v2 + v3;

    int x = tsum;
    for (int s = 1; s < 64; s <<= 1) {
        int y = __shfl_up(x, s, 64);
        if (lane >= s) x += y;
    }
    if (lane == 63) wsum[wid] = x;
    __syncthreads();
    if (wid == 0) {
        int w = (lane < 16) ? wsum[lane] : 0;
        for (int s = 1; s < 16; s <<= 1) {
            int y = __shfl_up(w, s, 64);
            if (lane >= s) w += y;
        }
        if (lane < 16) wsum[lane] = w;
    }
    __syncthreads();
    const int wpre = wid ? wsum[wid - 1] : 0;
    const int tpre = wpre + (x - tsum);
    if (base + 0 < Nn) off[base + 0] = tpre;
    if (base + 1 < Nn) off[base + 1] = tpre + v0;
    if (base + 2 < Nn) off[base + 2] = tpre + v0 + v1;
    if (base + 3 < Nn) off[base + 3] = tpre + v0 + v1 + v2;
    if (tid == 1023) bsum[blockIdx.x] = wsum[15];
}

// ===========================================================================
// MFMA helpers
// ===========================================================================
__device__ __forceinline__ floatx16 mfma16(half8 a, half8 b, floatx16 c) {
    return __builtin_amdgcn_mfma_f32_32x32x16_f16(a, b, c, 0, 0, 0);
}

__device__ __forceinline__ unsigned pkrtz(float a, float b) {
    union { fp16x2 h; unsigned u; } c;
    c.h = __builtin_amdgcn_cvt_pkrtz(a, b);
    return c.u;
}

__device__ __forceinline__ half8 hmax0(half8 v) {
#if __has_builtin(__builtin_elementwise_max)
    half8 z = {};
    return __builtin_elementwise_max(v, z);
#else
    #pragma unroll
    for (int i = 0; i < 8; ++i) v[i] = v[i] > (_Float16)0 ? v[i] : (_Float16)0;
    return v;
#endif
}

// packed-f16 bias+relu epilogue
__device__ __forceinline__ void pack_acc2(const floatx16& acc, half8 bA, half8 bB,
                                          unsigned* pk) {
    union { half8 h; unsigned u[4]; } c0, c1;
    #pragma unroll
    for (int q = 0; q < 4; ++q) c0.u[q] = pkrtz(acc[2 * q], acc[2 * q + 1]);
    #pragma unroll
    for (int q = 0; q < 4; ++q) c1.u[q] = pkrtz(acc[8 + 2 * q], acc[8 + 2 * q + 1]);
    c0.h = hmax0(c0.h + bA);
    c1.h = hmax0(c1.h + bB);
    pk[0] = c0.u[0]; pk[1] = c0.u[1]; pk[2] = c0.u[2]; pk[3] = c0.u[3];
    pk[4] = c1.u[0]; pk[5] = c1.u[1]; pk[6] = c1.u[2]; pk[7] = c1.u[3];
}

__device__ __forceinline__ void pack_acc_nb(const floatx16& acc, unsigned* pk) {
    union { half8 h; unsigned u[4]; } c0, c1;
    #pragma unroll
    for (int q = 0; q < 4; ++q) c0.u[q] = pkrtz(acc[2 * q], acc[2 * q + 1]);
    #pragma unroll
    for (int q = 0; q < 4; ++q) c1.u[q] = pkrtz(acc[8 + 2 * q], acc[8 + 2 * q + 1]);
    c0.h = hmax0(c0.h);
    c1.h = hmax0(c1.h);
    pk[0] = c0.u[0]; pk[1] = c0.u[1]; pk[2] = c0.u[2]; pk[3] = c0.u[3];
    pk[4] = c1.u[0]; pk[5] = c1.u[1]; pk[6] = c1.u[2]; pk[7] = c1.u[3];
}

__device__ __forceinline__ half8 frag_from_pk(const unsigned* pk, int s1, int kh) {
    const unsigned lo0 = pk[4 * s1], lo1 = pk[4 * s1 + 1];
    const unsigned hi0 = pk[4 * s1 + 2], hi1 = pk[4 * s1 + 3];
    const unsigned X0 = kh ? lo0 : hi0;
    const unsigned X1 = kh ? lo1 : hi1;
    const unsigned r0 = (unsigned)__shfl_xor((int)X0, 32, 64);
    const unsigned r1 = (unsigned)__shfl_xor((int)X1, 32, 64);
    union { half8 h; unsigned u[4]; } f;
    f.u[0] = kh ? r0 : lo0;
    f.u[1] = kh ? r1 : lo1;
    f.u[2] = kh ? hi0 : r0;
    f.u[3] = kh ? hi1 : r1;
    return f.h;
}

// ===========================================================================
// Fused fill+pq (R14, unchanged).
// ===========================================================================
__global__ __launch_bounds__(256) void fillpq_kernel(
    const int* __restrict__ ei, const int* __restrict__ off,
    const int* __restrict__ bsum, const int* __restrict__ rank,
    const float* __restrict__ cent,
    int4* __restrict__ sdd, float4* __restrict__ sums4,
    const float* __restrict__ z, const _Float16* __restrict__ wt,
    const float* __restrict__ bm1, _Float16* __restrict__ pq)
{
    const int tid = threadIdx.x;
    if (blockIdx.x < FILL_NB) {
        __shared__ int pb13[SCAN_NBLK];
        if (tid == 0) {
            int acc = 0;
            for (int i = 0; i < SCAN_NBLK; ++i) { pb13[i] = acc; acc += bsum[i]; }
        }
        __syncthreads();

        const int e = blockIdx.x * 256 + tid;
        const int s = ei[e];
        const int d = ei[Ee + e];
        sums4[e] = make_float4(0.f, 0.f, 0.f, 0.f);

        const float d0 = cent[d * 3 + 0] - cent[s * 3 + 0];
        const float d1 = cent[d * 3 + 1] - cent[s * 3 + 1];
        const float d2 = cent[d * 3 + 2] - cent[s * 3 + 2];
        const int p01 = (int)pkrtz(d0, d1);
        const int p2  = (int)pkrtz(d2, 0.0f);

        const int pos = off[d] + pb13[d >> 12] + rank[e];
        sdd[pos] = make_int4(s, d, p01, p2);
        return;
    }

    // ---- pq part ----
    const int wid = tid >> 6, lane = tid & 63;
    const int er = lane & 31, kh = lane >> 5;
    const int tile = ((blockIdx.x - FILL_NB) * 4 + wid) * 32;
    const int nclamp = (tile + er < Nn) ? (tile + er) : (Nn - 1);

    const float* __restrict__ zr = z + (size_t)nclamp * 64;
    half8 a[4];
    #pragma unroll
    for (int s = 0; s < 4; ++s) {
        const int base = s * 16 + kh * 8;
        const float4 u = *(const float4*)(zr + base);
        const float4 v = *(const float4*)(zr + base + 4);
        union { half8 h; unsigned w[4]; } hv;
        hv.w[0] = pkrtz(u.x, u.y);
        hv.w[1] = pkrtz(u.z, u.w);
        hv.w[2] = pkrtz(v.x, v.y);
        hv.w[3] = pkrtz(v.z, v.w);
        a[s] = hv.h;
    }

    const _Float16* __restrict__ wm1t = wt + WM1T;
    floatx16 P0, P1, Q0, Q1;
    const float b0 = bm1[er], b1 = bm1[32 + er];
    #pragma unroll
    for (int r = 0; r < 16; ++r) { P0[r] = b0; P1[r] = b1; Q0[r] = 0.f; Q1[r] = 0.f; }

    #pragma unroll
    for (int s = 0; s < 4; ++s) {
        const half8 wp0 = *(const half8*)(wm1t + er * 192 + s * 16 + kh * 8);
        const half8 wp1 = *(const half8*)(wm1t + (32 + er) * 192 + s * 16 + kh * 8);
        const half8 wq0 = *(const half8*)(wm1t + er * 192 + 64 + s * 16 + kh * 8);
        const half8 wq1 = *(const half8*)(wm1t + (32 + er) * 192 + 64 + s * 16 + kh * 8);
        P0 = mfma16(a[s], wp0, P0);
        P1 = mfma16(a[s], wp1, P1);
        Q0 = mfma16(a[s], wq0, Q0);
        Q1 = mfma16(a[s], wq1, Q1);
    }

    const int kh_t = (er >> 2) & 1;
    const int r_t = (er & 3) + 4 * ((er >> 3) & 3);
    #pragma unroll
    for (int r = 0; r < 16; ++r) {
        const int n = tile + (r & 3) + 8 * (r >> 2) + 4 * kh;
        if (n < Nn) {
            _Float16* row = pq + (size_t)n * 128;
            row[kh_t * 32 + r_t]           = (_Float16)P0[r];
            row[kh_t * 32 + 16 + r_t]      = (_Float16)P1[r];
            row[64 + kh_t * 32 + r_t]      = (_Float16)Q0[r];
            row[64 + kh_t * 32 + 16 + r_t] = (_Float16)Q1[r];
        }
    }
}

// ===========================================================================
// Edge kernel (R14 + __launch_bounds__(512,8): VGPR was 56 <= 64, so request
// full 32-wave/CU residency; LDS 4x30KB=120KB fits).
// ===========================================================================
__global__ __launch_bounds__(512, 8) void edge_mfma_kernel(
    const int4* __restrict__ sdd,
    const _Float16* __restrict__ wt, const _Float16* __restrict__ pq,
    const float* __restrict__ bm2,
    float* __restrict__ sums)
{
    __shared__ _Float16 swt[SWT_HALVES];   // 29952 B
    const int tid = threadIdx.x;
    const int wid = tid >> 6, lane = tid & 63;
    const int er = lane & 31;
    const int kh = lane >> 5;
    const int tile = (blockIdx.x * 8 + wid) * 32;   // 3125*8 = 25000 waves exact

    // ---- stage: We1 | We2 | Wm1c | Wm2 | pbias (1680 16B chunks) ----
    {
        const half8* __restrict__ g = (const half8*)wt;
        for (int i = tid; i < 1680; i += 512) {
            int gidx, dst;
            if (i < 128) {
                gidx = i;                       dst = SWE1 + i * 8;
            } else if (i < 640) {
                const int j = i - 128;
                gidx = 128 + j;                 dst = SWE2 + (j >> 3) * 72 + (j & 7) * 8;
            } else if (i < 1152) {
                const int j = i - 640;
                gidx = (WM1C >> 3) + j;         dst = SWM1C + (j >> 3) * 72 + (j & 7) * 8;
            } else if (i < 1664) {
                const int j = i - 1152;
                gidx = (WM2T >> 3) + j;         dst = SWM2 + (j >> 3) * 72 + (j & 7) * 8;
            } else {
                const int j = i - 1664;
                gidx = (PBIAS >> 3) + j;        dst = SPB + j * 8;
            }
            *(half8*)(swt + dst) = g[gidx];
        }
    }

    const int p = tile + er;
    const int4 ed = sdd[p];          // (src, dst, delta01, delta2_)

    // ---- PQ gathers: P[src] + Q[dst] segments (64B each) ----
    const half8* __restrict__ prow = (const half8*)(pq + (size_t)ed.x * 128 + kh * 32);
    const half8* __restrict__ qrow = (const half8*)(pq + (size_t)ed.y * 128 + 64 + kh * 32);
    const half8 pf0 = prow[0], pf1 = prow[1], pf2 = prow[2], pf3 = prow[3];
    const half8 qf0 = qrow[0], qf1 = qrow[1], qf2 = qrow[2], qf3 = qrow[3];

    __syncthreads();   // weights staged

    const _Float16* __restrict__ pbb = swt + SPB;
    const half8 b1A0 = *(const half8*)(pbb + kh * 16);
    const half8 b1A1 = *(const half8*)(pbb + kh * 16 + 8);
    const half8 b1B0 = *(const half8*)(pbb + 32 + kh * 16);
    const half8 b1B1 = *(const half8*)(pbb + 32 + kh * 16 + 8);
    const half8 b2A0 = *(const half8*)(pbb + 64 + kh * 16);
    const half8 b2A1 = *(const half8*)(pbb + 64 + kh * 16 + 8);
    const half8 b2B0 = *(const half8*)(pbb + 96 + kh * 16);
    const half8 b2B1 = *(const half8*)(pbb + 96 + kh * 16 + 8);

    // ---- e1' = (delta @ We1)^T : K=16 (3 real) ----
    half8 bdel;
    #pragma unroll
    for (int j = 0; j < 8; ++j) bdel[j] = (_Float16)0.0f;
    if (kh == 0) {
        union { int i; _Float16 h[2]; } u01, u2;
        u01.i = ed.z; u2.i = ed.w;
        bdel[0] = u01.h[0]; bdel[1] = u01.h[1]; bdel[2] = u2.h[0];
    }

    unsigned pk0[8], pk1[8];
    {
        floatx16 A0, A1;
        #pragma unroll
        for (int r = 0; r < 16; ++r) { A0[r] = 0.0f; A1[r] = 0.0f; }
        const half8 w0 = *(const half8*)(swt + SWE1 + er * 16 + kh * 8);
        const half8 w1 = *(const half8*)(swt + SWE1 + (32 + er) * 16 + kh * 8);
        A0 = mfma16(w0, bdel, A0);
        A1 = mfma16(w1, bdel, A1);
        pack_acc2(A0, b1A0, b1A1, pk0);
        pack_acc2(A1, b1B0, b1B1, pk1);
    }

    // ---- e2' = (e1 @ We2)^T : K=64 ----
    unsigned qk0[8], qk1[8];
    {
        floatx16 B0, B1;
        #pragma unroll
        for (int r = 0; r < 16; ++r) { B0[r] = 0.0f; B1[r] = 0.0f; }
        #pragma unroll
        for (int s = 0; s < 4; ++s) {
            const half8 act = frag_from_pk((s < 2) ? pk0 : pk1, s & 1, kh);
            const half8 w0 = *(const half8*)(swt + SWE2 + er * 72 + s * 16 + kh * 8);
            const half8 w1 = *(const half8*)(swt + SWE2 + (32 + er) * 72 + s * 16 + kh * 8);
            B0 = mfma16(w0, act, B0);
            B1 = mfma16(w1, act, B1);
        }
        pack_acc2(B0, b2A0, b2A1, qk0);
        pack_acc2(B1, b2B0, b2B1, qk1);
    }

    // ---- h1' : init = P[src]+Q[dst] (bm1 folded in P), + e2 @ Wm1c ----
    unsigned rk0[8], rk1[8];
    {
        floatx16 C0, C1;
        #pragma unroll
        for (int r = 0; r < 8; ++r) {
            C0[r]     = (float)pf0[r] + (float)qf0[r];
            C0[8 + r] = (float)pf1[r] + (float)qf1[r];
            C1[r]     = (float)pf2[r] + (float)qf2[r];
            C1[8 + r] = (float)pf3[r] + (float)qf3[r];
        }
        #pragma unroll
        for (int s = 0; s < 4; ++s) {
            const half8 act = frag_from_pk((s < 2) ? qk0 : qk1, s & 1, kh);
            const half8 w0 = *(const half8*)(swt + SWM1C + er * 72 + s * 16 + kh * 8);
            const half8 w1 = *(const half8*)(swt + SWM1C + (32 + er) * 72 + s * 16 + kh * 8);
            C0 = mfma16(w0, act, C0);
            C1 = mfma16(w1, act, C1);
        }
        pack_acc_nb(C0, rk0);
        pack_acc_nb(C1, rk1);
    }

    // ---- m = h1 @ Wm2 + bm2 : NORMAL orientation (edges in C-rows) ----
    floatx16 M0, M1;
    {
        const float bias0 = bm2[er], bias1 = bm2[32 + er];
        #pragma unroll
        for (int r = 0; r < 16; ++r) { M0[r] = bias0; M1[r] = bias1; }
        #pragma unroll
        for (int s = 0; s < 4; ++s) {
            const half8 act = frag_from_pk((s < 2) ? rk0 : rk1, s & 1, kh);
            const half8 w0 = *(const half8*)(swt + SWM2 + er * 72 + s * 16 + kh * 8);
            const half8 w1 = *(const half8*)(swt + SWM2 + (32 + er) * 72 + s * 16 + kh * 8);
            M0 = mfma16(act, w0, M0);
            M1 = mfma16(act, w1, M1);
        }
    }

    // ---- segmented (by dst) reduction + coalesced atomics ----
    const int dprev = __shfl(ed.y, (er + 31) & 31, 64);
    const bool boundary = (er == 0) || (ed.y != dprev);
    unsigned int m32 = (unsigned int)__ballot(boundary);

    while (m32) {
        const int a = __builtin_ctz(m32);
        m32 &= m32 - 1;
        const int b = m32 ? __builtin_ctz(m32) : 32;
        float p0 = 0.0f, p1 = 0.0f;
        #pragma unroll
        for (int r = 0; r < 16; ++r) {
            const int rrow = (r & 3) + 8 * (r >> 2) + 4 * kh;
            if (rrow >= a && rrow < b) { p0 += M0[r]; p1 += M1[r]; }
        }
        p0 += __shfl_xor(p0, 32, 64);
        p1 += __shfl_xor(p1, 32, 64);
        const float val = kh ? p1 : p0;
        const int dseg = __shfl(ed.y, a, 64);
        atomicAdd(&sums[(size_t)dseg * 64 + lane], val);
    }
}

// ===========================================================================
// Node kernel (MFMA): 512-thread blocks, 8 waves share one Wu staging.
// ===========================================================================
__global__ __launch_bounds__(512, 8) void node_mfma_kernel(
    const float* __restrict__ z, const _Float16* __restrict__ wu1t,
    const float* __restrict__ bu1, const int* __restrict__ deg,
    float* __restrict__ out)
{
    __shared__ _Float16 swu[64 * 136];
    const int tid = threadIdx.x;
    const int wid = tid >> 6, lane = tid & 63;
    const int er = lane & 31, kh = lane >> 5;
    const int tile = (blockIdx.x * 8 + wid) * 32;
    const int node = tile + er;

    {
        const half8* __restrict__ g = (const half8*)wu1t;
        for (int i = tid; i < 1024; i += 512) {
            const half8 v = g[i];
            const int n = i >> 4, c = i & 15;
            *(half8*)(swu + n * 136 + c * 8) = v;
        }
    }

    const int nclamp = (node < Nn) ? node : (Nn - 1);
    const int dn = deg[nclamp];
    const float scale = kh ? (1.0f / fmaxf((float)dn, 1.0f)) : 1.0f;
    const float* __restrict__ rowp = kh ? (out + (size_t)nclamp * 64)
                                        : (z + (size_t)nclamp * 64);
    half8 vreg[8];
    #pragma unroll
    for (int c = 0; c < 8; ++c) {
        const float4 a4 = *(const float4*)(rowp + c * 8);
        const float4 b4 = *(const float4*)(rowp + c * 8 + 4);
        union { half8 h; unsigned u[4]; } hv;
        hv.u[0] = pkrtz(a4.x * scale, a4.y * scale);
        hv.u[1] = pkrtz(a4.z * scale, a4.w * scale);
        hv.u[2] = pkrtz(b4.x * scale, b4.y * scale);
        hv.u[3] = pkrtz(b4.z * scale, b4.w * scale);
        vreg[c] = hv.h;
    }

    __syncthreads();

    floatx16 M0, M1;
    const float bias0 = bu1[er], bias1 = bu1[32 + er];
    #pragma unroll
    for (int r = 0; r < 16; ++r) { M0[r] = bias0; M1[r] = bias1; }
    #pragma unroll
    for (int s = 0; s < 4; ++s) {
        union { half8 h; int i[4]; } u;
        u.h = vreg[2 * s + 1];
        #pragma unroll
        for (int q = 0; q < 4; ++q) u.i[q] = __shfl_xor(u.i[q], 32, 64);
        const half8 act = kh ? u.h : vreg[2 * s];
        const half8 w0 = *(const half8*)(swu + er * 136 + s * 16 + kh * 8);
        const half8 w1 = *(const half8*)(swu + (32 + er) * 136 + s * 16 + kh * 8);
        M0 = mfma16(act, w0, M0);
        M1 = mfma16(act, w1, M1);
    }
    #pragma unroll
    for (int s = 0; s < 4; ++s) {
        union { half8 h; int i[4]; } u;
        u.h = vreg[2 * s];
        #pragma unroll
        for (int q = 0; q < 4; ++q) u.i[q] = __shfl_xor(u.i[q], 32, 64);
        const half8 act = kh ? vreg[2 * s + 1] : u.h;
        const half8 w0 = *(const half8*)(swu + er * 136 + 64 + s * 16 + kh * 8);
        const half8 w1 = *(const half8*)(swu + (32 + er) * 136 + 64 + s * 16 + kh * 8);
        M0 = mfma16(act, w0, M0);
        M1 = mfma16(act, w1, M1);
    }

    #pragma unroll
    for (int r = 0; r < 16; ++r) {
        const int rrow = (r & 3) + 8 * (r >> 2) + 4 * kh;
        const int nrow = tile + rrow;
        if (nrow < Nn) {
            out[(size_t)nrow * 64 + er]      = fmaxf(M0[r], 0.0f);
            out[(size_t)nrow * 64 + 32 + er] = fmaxf(M1[r], 0.0f);
        }
    }
}

// ===========================================================================
// Fallback (atomic, fp32) — only if ws_size too small. Known-correct (R1).
// ===========================================================================
__global__ __launch_bounds__(256) void edge_kernel_atomic(
    const float* __restrict__ z, const float* __restrict__ cent,
    const int* __restrict__ ei,
    const float* __restrict__ We1, const float* __restrict__ be1,
    const float* __restrict__ We2, const float* __restrict__ be2,
    const float* __restrict__ Wm1, const float* __restrict__ bm1,
    const float* __restrict__ Wm2, const float* __restrict__ bm2,
    float* __restrict__ sums, float* __restrict__ cnt)
{
    __shared__ float buf[64][256];
    const int tid = threadIdx.x;
    const int e = blockIdx.x * 256 + tid;
    const int src = ei[e];
    const int dst = ei[Ee + e];
    const float d0 = cent[dst * 3 + 0] - cent[src * 3 + 0];
    const float d1 = cent[dst * 3 + 1] - cent[src * 3 + 1];
    const float d2 = cent[dst * 3 + 2] - cent[src * 3 + 2];
    for (int j = 0; j < 64; ++j) {
        float v = fmaf(d0, We1[j], fmaf(d1, We1[64 + j], fmaf(d2, We1[128 + j], be1[j])));
        buf[j][tid] = fmaxf(v, 0.0f);
    }
    float acc[64];
    #pragma unroll
    for (int j = 0; j < 64; ++j) acc[j] = be2[j];
    for (int k = 0; k < 64; ++k) {
        const float ek = buf[k][tid];
        const float* wrow = We2 + k * 64;
        #pragma unroll
        for (int j = 0; j < 64; ++j) acc[j] = fmaf(ek, wrow[j], acc[j]);
    }
    #pragma unroll
    for (int j = 0; j < 64; ++j) buf[j][tid] = fmaxf(acc[j], 0.0f);
    #pragma unroll
    for (int j = 0; j < 64; ++j) acc[j] = bm1[j];
    const float* zs = z + src * 64;
    for (int k = 0; k < 64; ++k) {
        const float hk = zs[k];
        const float* wrow = Wm1 + k * 64;
        #pragma unroll
        for (int j = 0; j < 64; ++j) acc[j] = fmaf(hk, wrow[j], acc[j]);
    }
    const float* zd = z + dst * 64;
    for (int k = 0; k < 64; ++k) {
        const float hk = zd[k];
        const float* wrow = Wm1 + (64 + k) * 64;
        #pragma unroll
        for (int j = 0; j < 64; ++j) acc[j] = fmaf(hk, wrow[j], acc[j]);
    }
    for (int k = 0; k < 64; ++k) {
        const float hk = buf[k][tid];
        const float* wrow = Wm1 + (128 + k) * 64;
        #pragma unroll
        for (int j = 0; j < 64; ++j) acc[j] = fmaf(hk, wrow[j], acc[j]);
    }
    #pragma unroll
    for (int j = 0; j < 64; ++j) buf[j][tid] = fmaxf(acc[j], 0.0f);
    #pragma unroll
    for (int j = 0; j < 64; ++j) acc[j] = bm2[j];
    for (int k = 0; k < 64; ++k) {
        const float hk = buf[k][tid];
        const float* wrow = Wm2 + k * 64;
        #pragma unroll
        for (int j = 0; j < 64; ++j) acc[j] = fmaf(hk, wrow[j], acc[j]);
    }
    float* srow = sums + dst * 64;
    #pragma unroll
    for (int j = 0; j < 64; ++j) atomicAdd(&srow[j], acc[j]);
    atomicAdd(&cnt[dst], 1.0f);
}

__global__ __launch_bounds__(256) void node_kernel_atomic(
    const float* __restrict__ z,
    const float* __restrict__ Wu1, const float* __restrict__ bu1,
    float* __restrict__ out, const float* __restrict__ cnt)
{
    const int node = (blockIdx.x * 256 + threadIdx.x) >> 6;
    const int j = threadIdx.x & 63;
    const int base = node * 64;
    const float inv = 1.0f / fmaxf(cnt[node], 1.0f);
    const float zj = z[base + j];
    const float mj = out[base + j] * inv;
    float a = bu1[j];
    for (int k = 0; k < 64; ++k)
        a = fmaf(__shfl(zj, k, 64), Wu1[k * 64 + j], a);
    for (int k = 0; k < 64; ++k)
        a = fmaf(__shfl(mj, k, 64), Wu1[(64 + k) * 64 + j], a);
    out[base + j] = fmaxf(a, 0.0f);
}

extern "C" void kernel_launch(void* const* d_in, const int* in_sizes, int n_in,
                              void* d_out, int out_size, void* d_ws, size_t ws_size,
                              hipStream_t stream) {
    const float* z    = (const float*)d_in[0];
    const float* cent = (const float*)d_in[1];
    const int*   ei   = (const int*)d_in[2];
    const float* We1  = (const float*)d_in[3];
    const float* be1  = (const float*)d_in[4];
    const float* We2  = (const float*)d_in[5];
    const float* be2  = (const float*)d_in[6];
    const float* Wm1  = (const float*)d_in[7];
    const float* bm1  = (const float*)d_in[8];
    const float* Wm2  = (const float*)d_in[9];
    const float* bm2  = (const float*)d_in[10];
    const float* Wu1  = (const float*)d_in[11];
    const float* bu1  = (const float*)d_in[12];
    float* out = (float*)d_out;

    if (ws_size >= TOTAL_WS) {
        int4* sdd  = (int4*)((char*)d_ws + SDD_OFF);
        int* deg   = (int*)((char*)d_ws + DEG_OFF);
        int* off   = (int*)((char*)d_ws + OFF_OFF);
        int* bsum  = (int*)((char*)d_ws + BSUM_OFF);
        int* rank  = (int*)((char*)d_ws + RANK_OFF);
        _Float16* wt  = (_Float16*)((char*)d_ws + WT_OFF);
        _Float16* wu  = (_Float16*)((char*)d_ws + WU_OFF);
        _Float16* pq  = (_Float16*)((char*)d_ws + PQ_OFF);

        hipMemsetAsync(deg, 0, Nn * sizeof(int), stream);
        prep_kernel<<<PREP_NB, 256, 0, stream>>>(ei, We1, We2, Wm1, Wm2, Wu1,
                                                 be1, be2, wt, wu, deg, rank);
        scan1_kernel<<<SCAN_NBLK, 1024, 0, stream>>>(deg, off, bsum);
        fillpq_kernel<<<FILLPQ_NB, 256, 0, stream>>>(ei, off, bsum, rank, cent,
                                                     sdd, (float4*)out, z, wt, bm1, pq);
        edge_mfma_kernel<<<Ee / 256, 512, 0, stream>>>(sdd, wt, pq, bm2, out);
        node_mfma_kernel<<<(Nn + 255) / 256, 512, 0, stream>>>(z, wu, bu1, deg, out);
    } else {
        float* cnt = (float*)d_ws;
        hipMemsetAsync(out, 0, (size_t)Nn * 64 * sizeof(float), stream);
        hipMemsetAsync(cnt, 0, (size_t)Nn * sizeof(float), stream);
        edge_kernel_atomic<<<Ee / 256, 256, 0, stream>>>(z, cent, ei,
            We1, be1, We2, be2, Wm1, bm1, Wm2, bm2, out, cnt);
        node_kernel_atomic<<<Nn / 4, 256, 0, stream>>>(z, Wu1, bu1, out, cnt);
    }
}